// Round 4
// baseline (1321.843 us; speedup 1.0000x reference)
//
#include <hip/hip_runtime.h>

// MultiLatentHeadAttention on gfx950 — round 4.
// - GEMMs: split-bf16 3-term MFMA emulation, 32x32x16 shape, DMA staging,
//   swizzled LDS chunks (conflict-free).
// - attn1 (latents->4096 tokens) MFMA-ized flash kernel, P split hi/lo.
// - attn3 (tokens->latents) MFMA with P split hi/lo.

#define SEQ      4096
#define NHEADS   16
#define SCALE    0.125f   // 1/sqrt(64)

typedef short bfrag  __attribute__((ext_vector_type(8)));   // 8 x bf16
typedef float facc   __attribute__((ext_vector_type(4)));   // 16x16 accum
typedef float facc16 __attribute__((ext_vector_type(16)));  // 32x32 accum

__device__ __forceinline__ unsigned short f2bf(float f) {
  unsigned u = __float_as_uint(f);
  u += 0x7FFFu + ((u >> 16) & 1u);           // round-to-nearest-even
  return (unsigned short)(u >> 16);
}
__device__ __forceinline__ float bf2f(unsigned short h) {
  return __uint_as_float(((unsigned)h) << 16);
}
__device__ __forceinline__ unsigned pack_hl(float a, float b, unsigned &lo) {
  unsigned short ha = f2bf(a), hb = f2bf(b);
  unsigned short la = f2bf(a - bf2f(ha)), lb = f2bf(b - bf2f(hb));
  lo = (unsigned)la | ((unsigned)lb << 16);
  return (unsigned)ha | ((unsigned)hb << 16);
}
__device__ __forceinline__ void split8(const float* f, bfrag &h, bfrag &l) {
#pragma unroll
  for (int j = 0; j < 8; j++) {
    unsigned short hi = f2bf(f[j]);
    h[j] = (short)hi;
    l[j] = (short)f2bf(f[j] - bf2f(hi));
  }
}

__device__ __forceinline__ void gl_lds16(const void* g, void* l) {
  __builtin_amdgcn_global_load_lds(
      (const __attribute__((address_space(1))) void*)g,
      (__attribute__((address_space(3))) void*)l, 16, 0, 0);
}

// write 16 fp32 (scaled by inv) as bf16 hi/lo, 2x uint4 each
__device__ __forceinline__ void write_split16(unsigned short* Hp, unsigned short* Lp,
                                              const float* o, float inv) {
  uint4 H0, H1, L0, L1;
#pragma unroll
  for (int k = 0; k < 8; k++) {
    unsigned lo;
    unsigned hi = pack_hl(o[2*k] * inv, o[2*k+1] * inv, lo);
    if (k < 4) { (&H0.x)[k] = hi; (&L0.x)[k] = lo; }
    else       { (&H1.x)[k-4] = hi; (&L1.x)[k-4] = lo; }
  }
  *(uint4*)Hp       = H0;
  *(uint4*)(Hp + 8) = H1;
  *(uint4*)Lp       = L0;
  *(uint4*)(Lp + 8) = L1;
}

// ---------------------------------------------------------------------------
// Weight prep: W [K x N] fp32 -> Th/Tl [N x K] bf16 hi/lo (transpose+split)
// ---------------------------------------------------------------------------
__global__ __launch_bounds__(256) void prep_weight_kernel(
    const float* __restrict__ W, int K, int N,
    unsigned short* __restrict__ Th, unsigned short* __restrict__ Tl)
{
  __shared__ float tile[64][68];
  const int k0 = blockIdx.x * 64, n0 = blockIdx.y * 64;
  const int tid = threadIdx.x;
  const int r = tid >> 2, q = tid & 3;
#pragma unroll
  for (int j = 0; j < 4; j++)
    *(float4*)&tile[r][q*16 + j*4] =
        *(const float4*)&W[(size_t)(k0 + r) * N + n0 + q*16 + j*4];
  __syncthreads();
  const size_t obase = (size_t)(n0 + r) * K + k0 + q*16;
#pragma unroll
  for (int g = 0; g < 2; g++) {
    float f[8];
#pragma unroll
    for (int e = 0; e < 8; e++) f[e] = tile[q*16 + g*8 + e][r];
    uint4 H, Lo;
    H.x = pack_hl(f[0], f[1], Lo.x);
    H.y = pack_hl(f[2], f[3], Lo.y);
    H.z = pack_hl(f[4], f[5], Lo.z);
    H.w = pack_hl(f[6], f[7], Lo.w);
    *(uint4*)&Th[obase + g*8] = H;
    *(uint4*)&Tl[obase + g*8] = Lo;
  }
}

// ---------------------------------------------------------------------------
// Split fp32 array -> bf16 hi/lo (same layout). One thread per 8 elements.
// ---------------------------------------------------------------------------
__global__ __launch_bounds__(256) void split_f32_kernel(
    const float* __restrict__ X, unsigned short* __restrict__ H,
    unsigned short* __restrict__ Lo, int n8)
{
  int idx = blockIdx.x * 256 + threadIdx.x;
  if (idx >= n8) return;
  const float4 a = *(const float4*)&X[(size_t)idx*8];
  const float4 b = *(const float4*)&X[(size_t)idx*8 + 4];
  uint4 Hh, Ll;
  Hh.x = pack_hl(a.x, a.y, Ll.x);
  Hh.y = pack_hl(a.z, a.w, Ll.y);
  Hh.z = pack_hl(b.x, b.y, Ll.z);
  Hh.w = pack_hl(b.z, b.w, Ll.w);
  *(uint4*)&H[(size_t)idx*8]  = Hh;
  *(uint4*)&Lo[(size_t)idx*8] = Ll;
}

// ---------------------------------------------------------------------------
// Split-bf16 GEMM, DMA staging + chunk swizzle, 32x32x16 MFMA.
// C[MxN] fp32 = A (hi/lo bf16 [MxK]) @ B^T (hi/lo bf16 [NxK]).
// Block 256 / 4 waves; block tile 256x128; wave tile 128x64 (4m x 2n of
// 32x32); BK=32 (2 ksteps of 16). grid: (ceil(M/256), N/128).
// Content chunk c of row R lives at slot (c + (R>>1)) & 3.
// ---------------------------------------------------------------------------
__global__ __launch_bounds__(256, 2) void gemm_dma_kernel(
    const unsigned short* __restrict__ Ah, const unsigned short* __restrict__ Al,
    const unsigned short* __restrict__ Bh, const unsigned short* __restrict__ Bl,
    float* __restrict__ C, int M, int N, int K)
{
  __shared__ unsigned short sAh[256*32], sAl[256*32], sBh[128*32], sBl[128*32];
  const int tid = threadIdx.x;
  const int m0 = blockIdx.x * 256, n0 = blockIdx.y * 128;
  const int wave = tid >> 6, lane = tid & 63;
  const int lrow = lane & 31, lh = lane >> 5;
  const int wm = (wave & 1) * 128, wn = (wave >> 1) * 64;

  // staging: each wave-instr moves 16 rows x 64B (lane -> row lane>>2,
  // slot chunk lane&3; content chunk = (slot - (R>>1)) & 3).
  const int srow = lane >> 2, schunk = lane & 3;
  size_t aoff[4], boff[2];
#pragma unroll
  for (int j = 0; j < 4; j++) {
    const int R = 64*wave + 16*j + srow;
    int rg = m0 + R;
    if (rg > M-1) rg = M-1;
    const int c = (schunk - (R >> 1)) & 3;
    aoff[j] = ((size_t)rg * K + c*8) * 2;
  }
#pragma unroll
  for (int j = 0; j < 2; j++) {
    const int R = 32*wave + 16*j + srow;
    const int rg = n0 + R;
    const int c = (schunk - (R >> 1)) & 3;
    boff[j] = ((size_t)rg * K + c*8) * 2;
  }
  const char* Ahc = (const char*)Ah;  const char* Alc = (const char*)Al;
  const char* Bhc = (const char*)Bh;  const char* Blc = (const char*)Bl;

  facc16 acc[4][2] = {};   // [mi][ni]

  for (int k0 = 0; k0 < K; k0 += 32) {
    const size_t kb = (size_t)k0 * 2;
#pragma unroll
    for (int j = 0; j < 4; j++) {
      gl_lds16(Ahc + aoff[j] + kb, (char*)sAh + (64*wave + 16*j)*64);
      gl_lds16(Alc + aoff[j] + kb, (char*)sAl + (64*wave + 16*j)*64);
    }
#pragma unroll
    for (int j = 0; j < 2; j++) {
      gl_lds16(Bhc + boff[j] + kb, (char*)sBh + (32*wave + 16*j)*64);
      gl_lds16(Blc + boff[j] + kb, (char*)sBl + (32*wave + 16*j)*64);
    }
    __syncthreads();   // DMA complete + all waves at barrier

#pragma unroll
    for (int ks = 0; ks < 2; ks++) {
      const int cc = ks*2 + lh;            // content chunk for k = ks*16 + lh*8
      bfrag bh[2], bl[2];
#pragma unroll
      for (int ni = 0; ni < 2; ni++) {
        const int R = wn + ni*32 + lrow;
        const int slot = (cc + (R >> 1)) & 3;
        const int bo = R*32 + slot*8;
        bh[ni] = *(const bfrag*)&sBh[bo];
        bl[ni] = *(const bfrag*)&sBl[bo];
      }
#pragma unroll
      for (int mi = 0; mi < 4; mi++) {
        const int R = wm + mi*32 + lrow;
        const int slot = (cc + (R >> 1)) & 3;
        const int ao = R*32 + slot*8;
        const bfrag ah = *(const bfrag*)&sAh[ao];
        const bfrag al = *(const bfrag*)&sAl[ao];
#pragma unroll
        for (int ni = 0; ni < 2; ni++) {
          acc[mi][ni] = __builtin_amdgcn_mfma_f32_32x32x16_bf16(ah, bh[ni], acc[mi][ni], 0, 0, 0);
          acc[mi][ni] = __builtin_amdgcn_mfma_f32_32x32x16_bf16(ah, bl[ni], acc[mi][ni], 0, 0, 0);
          acc[mi][ni] = __builtin_amdgcn_mfma_f32_32x32x16_bf16(al, bh[ni], acc[mi][ni], 0, 0, 0);
        }
      }
    }
    __syncthreads();
  }

  // epilogue: 32x32 C/D layout col=lane&31, row=(reg&3)+8*(reg>>2)+4*(lane>>5)
#pragma unroll
  for (int mi = 0; mi < 4; mi++) {
#pragma unroll
    for (int g = 0; g < 4; g++) {
#pragma unroll
      for (int r = 0; r < 4; r++) {
        const int row = m0 + wm + mi*32 + g*8 + lh*4 + r;
        if (row < M) {
          float* Crow = C + (size_t)row * N + n0 + wn + lrow;
          Crow[0]  = acc[mi][0][g*4 + r];
          Crow[32] = acc[mi][1][g*4 + r];
        }
      }
    }
  }
}

// ---------------------------------------------------------------------------
// Stage-1 cross attention, MFMA flash. 64 latents attend to 4096 tokens.
// grid: (8 chunks, H, B), block 256 = 4 waves; wave owns 16 latent rows.
// Per 64-token tile: cooperative K split-stage ([tok][dim] bf16 h/l),
// V fp32 stage + transpose-split ([dim][tok] bf16 h/l); S via 3-term MFMA;
// online softmax in C-layout; P split hi/lo via LDS; PV 3-term MFMA.
// ---------------------------------------------------------------------------
__global__ __launch_bounds__(256) void attn1_kernel(
    const float* __restrict__ Qlat,   // [64 x 1024]
    const float* __restrict__ KV,     // [B*T x 3072], K cols 0..1023, V 1024..2047
    float* __restrict__ mPart, float* __restrict__ lPart, float* __restrict__ oPart)
{
  __shared__ unsigned short Kh[64][72], Kl[64][72];
  __shared__ float Vs[64][68];
  __shared__ unsigned short Vth[64][72], Vtl[64][72];
  __shared__ unsigned short Pbh[4][16][72], Pbl[4][16][72];
  const int tid = threadIdx.x;
  const int wave = tid >> 6, lane = tid & 63;
  const int lrow = lane & 15, lq = lane >> 4;
  const int chunk = blockIdx.x, h = blockIdx.y, b = blockIdx.z;

  // Q A-frags: m = latent = wave*16 + lrow, k = ks*32 + lq*8 + j
  bfrag qh[2], ql[2];
  {
    const float* qp = Qlat + (size_t)(wave*16 + lrow)*1024 + h*64 + lq*8;
#pragma unroll
    for (int ks = 0; ks < 2; ks++) {
      float f[8];
      *(float4*)&f[0] = *(const float4*)(qp + ks*32);
      *(float4*)&f[4] = *(const float4*)(qp + ks*32 + 4);
      split8(f, qh[ks], ql[ks]);
    }
  }
  float m_i[4], l_i[4];
  facc o[4] = {};
#pragma unroll
  for (int r = 0; r < 4; r++) { m_i[r] = -__builtin_inff(); l_i[r] = 0.f; }

  const int stok = tid >> 2, sq = (tid & 3) * 16;   // staging: token, dim base
  const int td = tid >> 2, tg = (tid & 3) * 16;     // transpose: dim, token base

  for (int kt = 0; kt < 8; kt++) {
    // ---- stage K (split) + V (fp32)
    {
      const size_t rb = ((size_t)b*SEQ + chunk*512 + kt*64 + stok)*3072 + h*64 + sq;
      float f[16];
      *(float4*)&f[0]  = *(const float4*)&KV[rb];
      *(float4*)&f[4]  = *(const float4*)&KV[rb + 4];
      *(float4*)&f[8]  = *(const float4*)&KV[rb + 8];
      *(float4*)&f[12] = *(const float4*)&KV[rb + 12];
      bfrag h0, l0, h1, l1;
      split8(f, h0, l0);
      split8(f + 8, h1, l1);
      *(bfrag*)&Kh[stok][sq]     = h0;
      *(bfrag*)&Kh[stok][sq + 8] = h1;
      *(bfrag*)&Kl[stok][sq]     = l0;
      *(bfrag*)&Kl[stok][sq + 8] = l1;
      *(float4*)&Vs[stok][sq]      = *(const float4*)&KV[rb + 1024];
      *(float4*)&Vs[stok][sq + 4]  = *(const float4*)&KV[rb + 1028];
      *(float4*)&Vs[stok][sq + 8]  = *(const float4*)&KV[rb + 1032];
      *(float4*)&Vs[stok][sq + 12] = *(const float4*)&KV[rb + 1036];
    }
    __syncthreads();
    // ---- transpose-split V: thread owns dim td, tokens tg..tg+15
    {
      float f[16];
#pragma unroll
      for (int u = 0; u < 16; u++) f[u] = Vs[tg + u][td];
      bfrag h0, l0, h1, l1;
      split8(f, h0, l0);
      split8(f + 8, h1, l1);
      *(bfrag*)&Vth[td][tg]     = h0;
      *(bfrag*)&Vth[td][tg + 8] = h1;
      *(bfrag*)&Vtl[td][tg]     = l0;
      *(bfrag*)&Vtl[td][tg + 8] = l1;
    }
    __syncthreads();
    // ---- S = Q @ K^T  (m=latent16, n=token64, k=dim64)
    facc s[4] = {};
#pragma unroll
    for (int ni = 0; ni < 4; ni++) {
#pragma unroll
      for (int ks = 0; ks < 2; ks++) {
        const bfrag kbh = *(const bfrag*)&Kh[ni*16 + lrow][ks*32 + lq*8];
        const bfrag kbl = *(const bfrag*)&Kl[ni*16 + lrow][ks*32 + lq*8];
        s[ni] = __builtin_amdgcn_mfma_f32_16x16x32_bf16(qh[ks], kbh, s[ni], 0, 0, 0);
        s[ni] = __builtin_amdgcn_mfma_f32_16x16x32_bf16(qh[ks], kbl, s[ni], 0, 0, 0);
        s[ni] = __builtin_amdgcn_mfma_f32_16x16x32_bf16(ql[ks], kbh, s[ni], 0, 0, 0);
      }
    }
    // ---- online softmax (rows r: latent lq*4+r; cols: ni*16+lrow)
#pragma unroll
    for (int r = 0; r < 4; r++) {
      float mx = fmaxf(fmaxf(s[0][r], s[1][r]), fmaxf(s[2][r], s[3][r])) * SCALE;
      mx = fmaxf(mx, __shfl_xor(mx, 1));
      mx = fmaxf(mx, __shfl_xor(mx, 2));
      mx = fmaxf(mx, __shfl_xor(mx, 4));
      mx = fmaxf(mx, __shfl_xor(mx, 8));
      const float m_new = fmaxf(m_i[r], mx);
      const float fac = __expf(m_i[r] - m_new);
      m_i[r] = m_new;
      float sum = 0.f;
#pragma unroll
      for (int ni = 0; ni < 4; ni++) {
        const float p = __expf(s[ni][r] * SCALE - m_new);
        sum += p;
        const unsigned short ph = f2bf(p);
        Pbh[wave][lq*4 + r][ni*16 + lrow] = ph;
        Pbl[wave][lq*4 + r][ni*16 + lrow] = f2bf(p - bf2f(ph));
      }
      sum += __shfl_xor(sum, 1);
      sum += __shfl_xor(sum, 2);
      sum += __shfl_xor(sum, 4);
      sum += __shfl_xor(sum, 8);
      l_i[r] = l_i[r] * fac + sum;
#pragma unroll
      for (int nd = 0; nd < 4; nd++) o[nd][r] *= fac;
    }
    __asm__ volatile("s_waitcnt lgkmcnt(0)" ::: "memory");   // same-wave P visible
    bfrag pah[2], pal[2];
#pragma unroll
    for (int ks = 0; ks < 2; ks++) {
      pah[ks] = *(const bfrag*)&Pbh[wave][lrow][ks*32 + lq*8];
      pal[ks] = *(const bfrag*)&Pbl[wave][lrow][ks*32 + lq*8];
    }
    // ---- O += P @ V  (m=latent16, n=dim64, k=token64)
#pragma unroll
    for (int nd = 0; nd < 4; nd++) {
#pragma unroll
      for (int ks = 0; ks < 2; ks++) {
        const bfrag vbh = *(const bfrag*)&Vth[nd*16 + lrow][ks*32 + lq*8];
        const bfrag vbl = *(const bfrag*)&Vtl[nd*16 + lrow][ks*32 + lq*8];
        o[nd] = __builtin_amdgcn_mfma_f32_16x16x32_bf16(pah[ks], vbh, o[nd], 0, 0, 0);
        o[nd] = __builtin_amdgcn_mfma_f32_16x16x32_bf16(pal[ks], vbh, o[nd], 0, 0, 0);
        o[nd] = __builtin_amdgcn_mfma_f32_16x16x32_bf16(pah[ks], vbl, o[nd], 0, 0, 0);
      }
    }
    __syncthreads();   // LDS reuse next iter
  }
  // ---- partials (unnormalized o, plus m/l)
  const int bh = b*NHEADS + h;
  const int lat0 = wave*16 + lq*4;
#pragma unroll
  for (int r = 0; r < 4; r++) {
    const size_t ob = ((size_t)(bh*8 + chunk)*64 + lat0 + r)*64;
#pragma unroll
    for (int nd = 0; nd < 4; nd++)
      oPart[ob + nd*16 + lrow] = o[nd][r];
    if (lrow == 0) {
      mPart[(bh*8 + chunk)*64 + lat0 + r] = m_i[r];
      lPart[(bh*8 + chunk)*64 + lat0 + r] = l_i[r];
    }
  }
}

// combine 8 flash partials -> z [B*64 x 1024] as bf16 hi/lo. grid (H, B).
__global__ __launch_bounds__(256) void attn1_combine_kernel(
    const float* __restrict__ mPart, const float* __restrict__ lPart,
    const float* __restrict__ oPart,
    unsigned short* __restrict__ Zh, unsigned short* __restrict__ Zl)
{
  const int h = blockIdx.x, b = blockIdx.y;
  const int tid = threadIdx.x;
  const int i = tid >> 2, q = tid & 3, db = q * 16;
  const int bh = b*NHEADS + h;
  float mv[8];
  float M = -__builtin_inff();
#pragma unroll
  for (int c = 0; c < 8; c++) { mv[c] = mPart[(bh*8 + c)*64 + i]; M = fmaxf(M, mv[c]); }
  float Lt = 0.f, w[8];
#pragma unroll
  for (int c = 0; c < 8; c++) { w[c] = __expf(mv[c] - M); Lt += lPart[(bh*8 + c)*64 + i] * w[c]; }
  float o[16];
#pragma unroll
  for (int dd = 0; dd < 16; dd++) o[dd] = 0.f;
#pragma unroll
  for (int c = 0; c < 8; c++) {
    const float* ob = oPart + ((size_t)(bh*8 + c)*64 + i)*64 + db;
#pragma unroll
    for (int dd = 0; dd < 16; dd += 4) {
      const float4 v = *(const float4*)(ob + dd);
      o[dd+0] += w[c]*v.x; o[dd+1] += w[c]*v.y; o[dd+2] += w[c]*v.z; o[dd+3] += w[c]*v.w;
    }
  }
  const float inv = 1.f / Lt;
  const size_t ob2 = ((size_t)b*64 + i)*1024 + h*64 + db;
  write_split16(Zh + ob2, Zl + ob2, o, inv);
}

// ---------------------------------------------------------------------------
// Small attention (64 keys), stage 2. fp32 VALU path (tiny: 64 blocks).
// ---------------------------------------------------------------------------
__global__ __launch_bounds__(256) void attn_small_kernel(
    const float* __restrict__ Qp, int ldq, int qrows_per_b,
    const float* __restrict__ Kp, int ldk,
    const float* __restrict__ Vp, int ldv,
    unsigned short* __restrict__ Oh, unsigned short* __restrict__ Ol, int ldo)
{
  __shared__ float Ks[64][68], Vs[64][68], Ps[64][68];
  const int tid = threadIdx.x;
  const int tt = blockIdx.x, h = blockIdx.y, b = blockIdx.z;
  const int i = tid >> 2, q = tid & 3, db = q * 16, rot = q * 20;
  const size_t qrow = (size_t)b*qrows_per_b + (size_t)tt*64 + i;
  const size_t krow = (size_t)b*64 + i;

  float4 qreg[16];
#pragma unroll
  for (int dd = 0; dd < 16; dd++) {
    const int c = (4*dd + rot) & 63;
    qreg[dd] = *(const float4*)&Qp[qrow*ldq + h*64 + c];
  }
#pragma unroll
  for (int jj = 0; jj < 4; jj++) {
    *(float4*)&Ks[i][db + jj*4] = *(const float4*)&Kp[krow*ldk + h*64 + db + jj*4];
    *(float4*)&Vs[i][db + jj*4] = *(const float4*)&Vp[krow*ldv + h*64 + db + jj*4];
  }
  __syncthreads();

  float s[16];
#pragma unroll
  for (int jj = 0; jj < 16; jj++) {
    const int j = db + jj;
    float4 a4 = make_float4(0.f, 0.f, 0.f, 0.f);
#pragma unroll
    for (int dd = 0; dd < 16; dd++) {
      const int c = (4*dd + rot) & 63;
      const float4 kv = *(const float4*)&Ks[j][c];
      a4.x += qreg[dd].x*kv.x; a4.y += qreg[dd].y*kv.y;
      a4.z += qreg[dd].z*kv.z; a4.w += qreg[dd].w*kv.w;
    }
    s[jj] = (a4.x + a4.y + a4.z + a4.w) * SCALE;
  }
  float m = s[0];
#pragma unroll
  for (int jj = 1; jj < 16; jj++) m = fmaxf(m, s[jj]);
  m = fmaxf(m, __shfl_xor(m, 1));
  m = fmaxf(m, __shfl_xor(m, 2));
  float l = 0.f;
#pragma unroll
  for (int jj = 0; jj < 16; jj++) {
    const float p = __expf(s[jj] - m);
    Ps[i][db + jj] = p;
    l += p;
  }
  l += __shfl_xor(l, 1);
  l += __shfl_xor(l, 2);
  __syncthreads();
  float o[16];
#pragma unroll
  for (int dd = 0; dd < 16; dd++) o[dd] = 0.f;
  for (int j = 0; j < 64; j++) {
    const float w = Ps[i][j];
#pragma unroll
    for (int dd = 0; dd < 16; dd += 4) {
      const float4 vv = *(const float4*)&Vs[j][db + dd];
      o[dd+0] += w*vv.x; o[dd+1] += w*vv.y; o[dd+2] += w*vv.z; o[dd+3] += w*vv.w;
    }
  }
  const float inv = 1.f / l;
  const size_t ob = qrow*ldo + h*64 + db;
  write_split16(Oh + ob, Ol + ob, o, inv);
}

// ---------------------------------------------------------------------------
// Stage-3 attention, MFMA. 16384 tokens attend to 64 latents.
// grid: (64 qtiles, H, B), block 256 = 4 waves; wave: 16 q-rows.
// P split hi/lo (3-term PV).
// ---------------------------------------------------------------------------
__global__ __launch_bounds__(256) void attn3_mfma_kernel(
    const float* __restrict__ QKV,    // [16384 x 3072], Qx at cols 2048..3071
    const float* __restrict__ z2kv,   // [256 x 2048], Kz cols 0..1023, Vz 1024..2047
    unsigned short* __restrict__ Oh, unsigned short* __restrict__ Ol)  // [16384 x 1024]
{
  __shared__ unsigned short Pbh[4][16][72], Pbl[4][16][72];
  const int tid = threadIdx.x;
  const int wave = tid >> 6, lane = tid & 63;
  const int lrow = lane & 15, lq = lane >> 4;
  const int qt = blockIdx.x, h = blockIdx.y, b = blockIdx.z;
  const size_t tok0 = (size_t)b*SEQ + qt*64 + wave*16;

  // Q A-frags
  bfrag qh[2], ql[2];
  {
    const float* qp = QKV + (tok0 + lrow)*3072 + 2048 + h*64 + lq*8;
#pragma unroll
    for (int ks = 0; ks < 2; ks++) {
      float f[8];
      *(float4*)&f[0] = *(const float4*)(qp + ks*32);
      *(float4*)&f[4] = *(const float4*)(qp + ks*32 + 4);
      split8(f, qh[ks], ql[ks]);
    }
  }
  // Kz B-frags
  bfrag kh[4][2], kl[4][2];
#pragma unroll
  for (int ni = 0; ni < 4; ni++) {
    const float* kp = z2kv + (size_t)(b*64 + ni*16 + lrow)*2048 + h*64 + lq*8;
#pragma unroll
    for (int ks = 0; ks < 2; ks++) {
      float f[8];
      *(float4*)&f[0] = *(const float4*)(kp + ks*32);
      *(float4*)&f[4] = *(const float4*)(kp + ks*32 + 4);
      split8(f, kh[ni][ks], kl[ni][ks]);
    }
  }
  // S = Q @ Kz^T
  facc s[4] = {};
#pragma unroll
  for (int ni = 0; ni < 4; ni++)
#pragma unroll
    for (int ks = 0; ks < 2; ks++) {
      s[ni] = __builtin_amdgcn_mfma_f32_16x16x32_bf16(qh[ks], kh[ni][ks], s[ni], 0, 0, 0);
      s[ni] = __builtin_amdgcn_mfma_f32_16x16x32_bf16(qh[ks], kl[ni][ks], s[ni], 0, 0, 0);
      s[ni] = __builtin_amdgcn_mfma_f32_16x16x32_bf16(ql[ks], kh[ni][ks], s[ni], 0, 0, 0);
    }
  // softmax + P split
  float inv[4];
#pragma unroll
  for (int r = 0; r < 4; r++) {
    float mx = fmaxf(fmaxf(s[0][r], s[1][r]), fmaxf(s[2][r], s[3][r])) * SCALE;
    mx = fmaxf(mx, __shfl_xor(mx, 1));
    mx = fmaxf(mx, __shfl_xor(mx, 2));
    mx = fmaxf(mx, __shfl_xor(mx, 4));
    mx = fmaxf(mx, __shfl_xor(mx, 8));
    float sum = 0.f;
#pragma unroll
    for (int ni = 0; ni < 4; ni++) {
      const float p = __expf(s[ni][r] * SCALE - mx);
      sum += p;
      const unsigned short ph = f2bf(p);
      Pbh[wave][lq*4 + r][ni*16 + lrow] = ph;
      Pbl[wave][lq*4 + r][ni*16 + lrow] = f2bf(p - bf2f(ph));
    }
    sum += __shfl_xor(sum, 1);
    sum += __shfl_xor(sum, 2);
    sum += __shfl_xor(sum, 4);
    sum += __shfl_xor(sum, 8);
    inv[r] = 1.f / sum;
  }
  __asm__ volatile("s_waitcnt lgkmcnt(0)" ::: "memory");
  bfrag pah[2], pal[2];
#pragma unroll
  for (int ks = 0; ks < 2; ks++) {
    pah[ks] = *(const bfrag*)&Pbh[wave][lrow][ks*32 + lq*8];
    pal[ks] = *(const bfrag*)&Pbl[wave][lrow][ks*32 + lq*8];
  }
  // O = P @ Vz
  facc o[4] = {};
#pragma unroll
  for (int ni = 0; ni < 4; ni++) {
#pragma unroll
    for (int ks = 0; ks < 2; ks++) {
      float f[8];
#pragma unroll
      for (int jj = 0; jj < 8; jj++)
        f[jj] = z2kv[(size_t)(b*64 + ks*32 + lq*8 + jj)*2048 + 1024 + h*64 + ni*16 + lrow];
      bfrag vh, vl;
      split8(f, vh, vl);
      o[ni] = __builtin_amdgcn_mfma_f32_16x16x32_bf16(pah[ks], vh, o[ni], 0, 0, 0);
      o[ni] = __builtin_amdgcn_mfma_f32_16x16x32_bf16(pal[ks], vh, o[ni], 0, 0, 0);
      o[ni] = __builtin_amdgcn_mfma_f32_16x16x32_bf16(pah[ks], vl, o[ni], 0, 0, 0);
    }
  }
  // epilogue: split bf16 out
#pragma unroll
  for (int ni = 0; ni < 4; ni++) {
#pragma unroll
    for (int r = 0; r < 4; r++) {
      const float v = o[ni][r] * inv[r];
      const unsigned short hi = f2bf(v);
      const unsigned short lo = f2bf(v - bf2f(hi));
      const size_t idx = (tok0 + lq*4 + r)*1024 + h*64 + ni*16 + lrow;
      Oh[idx] = hi;
      Ol[idx] = lo;
    }
  }
}

// ---------------------------------------------------------------------------
extern "C" void kernel_launch(void* const* d_in, const int* in_sizes, int n_in,
                              void* d_out, int out_size, void* d_ws, size_t ws_size,
                              hipStream_t stream)
{
  const float* x      = (const float*)d_in[0];
  const float* L      = (const float*)d_in[1];
  const float* Wq_lat = (const float*)d_in[2];
  const float* Wk_in  = (const float*)d_in[3];
  const float* Wv_in  = (const float*)d_in[4];
  const float* Wq_in  = (const float*)d_in[5];
  const float* Wk_lat = (const float*)d_in[6];
  const float* Wv_lat = (const float*)d_in[7];
  const float* Wout   = (const float*)d_in[8];
  float* out = (float*)d_out;
  (void)in_sizes; (void)n_in; (void)out_size; (void)ws_size;

  char* ws = (char*)d_ws;
  size_t off = 0;
  auto alloc = [&](size_t bytes) -> char* {
    char* p = ws + off; off += (bytes + 255) & ~(size_t)255; return p;
  };
  unsigned short* wtKVQ_h = (unsigned short*)alloc(3072ull*2048*2);
  unsigned short* wtKVQ_l = (unsigned short*)alloc(3072ull*2048*2);
  unsigned short* wtLat_h = (unsigned short*)alloc(3072ull*1024*2);
  unsigned short* wtLat_l = (unsigned short*)alloc(3072ull*1024*2);
  unsigned short* wtOut_h = (unsigned short*)alloc(2048ull*1024*2);
  unsigned short* wtOut_l = (unsigned short*)alloc(2048ull*1024*2);
  unsigned short* xh    = (unsigned short*)alloc(16384ull*2048*2);
  unsigned short* xl    = (unsigned short*)alloc(16384ull*2048*2);
  unsigned short* Lh    = (unsigned short*)alloc(64ull*1024*2);
  unsigned short* Ll    = (unsigned short*)alloc(64ull*1024*2);
  unsigned short* zh    = (unsigned short*)alloc(256ull*1024*2);
  unsigned short* zl    = (unsigned short*)alloc(256ull*1024*2);
  unsigned short* z2h   = (unsigned short*)alloc(256ull*1024*2);
  unsigned short* z2l   = (unsigned short*)alloc(256ull*1024*2);
  float* qlat  = (float*)alloc(64ull*1024*4);
  float* zqkv  = (float*)alloc(256ull*3072*4);
  float* z2kv  = (float*)alloc(256ull*2048*4);
  float* mPart = (float*)alloc(4ull*16*8*64*4);
  float* lPart = (float*)alloc(4ull*16*8*64*4);
  float* oPart = (float*)alloc(4ull*16*8*64*64*4);
  float* qkv   = (float*)alloc(16384ull*3072*4);   // [K|V|Qx]
  unsigned short* xlat_h = xh;   // reuse (dead after fused QKV GEMM)
  unsigned short* xlat_l = xl;

  dim3 blk(256);

  // 1) weight prep
  prep_weight_kernel<<<dim3(32, 16), blk, 0, stream>>>(Wk_in, 2048, 1024, wtKVQ_h, wtKVQ_l);
  prep_weight_kernel<<<dim3(32, 16), blk, 0, stream>>>(Wv_in, 2048, 1024, wtKVQ_h + 1024ull*2048, wtKVQ_l + 1024ull*2048);
  prep_weight_kernel<<<dim3(32, 16), blk, 0, stream>>>(Wq_in, 2048, 1024, wtKVQ_h + 2048ull*2048, wtKVQ_l + 2048ull*2048);
  prep_weight_kernel<<<dim3(16, 16), blk, 0, stream>>>(Wq_lat, 1024, 1024, wtLat_h, wtLat_l);
  prep_weight_kernel<<<dim3(16, 16), blk, 0, stream>>>(Wk_lat, 1024, 1024, wtLat_h + 1024ull*1024, wtLat_l + 1024ull*1024);
  prep_weight_kernel<<<dim3(16, 16), blk, 0, stream>>>(Wv_lat, 1024, 1024, wtLat_h + 2048ull*1024, wtLat_l + 2048ull*1024);
  prep_weight_kernel<<<dim3(16, 32), blk, 0, stream>>>(Wout, 1024, 2048, wtOut_h, wtOut_l);
  split_f32_kernel<<<dim3(16384), blk, 0, stream>>>(x, xh, xl, 16384*2048/8);
  split_f32_kernel<<<dim3(32), blk, 0, stream>>>(L, Lh, Ll, 64*1024/8);

  // 2) Q_lat = L @ W_q_lat  [64 x 1024]
  gemm_dma_kernel<<<dim3(1, 8), blk, 0, stream>>>(Lh, Ll, wtLat_h, wtLat_l, qlat, 64, 1024, 1024);
  // 3) [K|V|Qx] = x @ [Wk_in|Wv_in|Wq_in]  [16384 x 3072]
  gemm_dma_kernel<<<dim3(64, 24), blk, 0, stream>>>(xh, xl, wtKVQ_h, wtKVQ_l, qkv, 16384, 3072, 2048);
  // 4) stage-1 flash attention (MFMA) -> z (split)
  attn1_kernel<<<dim3(8, 16, 4), blk, 0, stream>>>(qlat, qkv, mPart, lPart, oPart);
  attn1_combine_kernel<<<dim3(16, 4), blk, 0, stream>>>(mPart, lPart, oPart, zh, zl);
  // 5) [Ql|Kl|Vl] = z @ [Wq_lat|Wk_lat|Wv_lat]  [256 x 3072]
  gemm_dma_kernel<<<dim3(1, 24), blk, 0, stream>>>(zh, zl, wtLat_h, wtLat_l, zqkv, 256, 3072, 1024);
  // 6) stage-2 latent self-attention -> z2 (split)
  attn_small_kernel<<<dim3(1, 16, 4), blk, 0, stream>>>(zqkv, 3072, 64, zqkv + 1024, 3072, zqkv + 2048, 3072, z2h, z2l, 1024);
  // 7) [Kz|Vz] = z2 @ [Wk_lat|Wv_lat]  [256 x 2048]
  gemm_dma_kernel<<<dim3(1, 16), blk, 0, stream>>>(z2h, z2l, wtLat_h + 1024ull*1024, wtLat_l + 1024ull*1024, z2kv, 256, 2048, 1024);
  // 8) stage-3 attention (MFMA) -> x_latent (split)
  attn3_mfma_kernel<<<dim3(64, 16, 4), blk, 0, stream>>>(qkv, z2kv, xlat_h, xlat_l);
  // 9) out = x_latent @ W_out  [16384 x 2048]
  gemm_dma_kernel<<<dim3(64, 16), blk, 0, stream>>>(xlat_h, xlat_l, wtOut_h, wtOut_l, out, 16384, 2048, 1024);
}